// Round 2
// baseline (282.749 us; speedup 1.0000x reference)
//
#include <hip/hip_runtime.h>
#include <math.h>

// Problem constants
#define M_ROWS   8192     // B*S
#define N_CODES  16384
#define D_DIM    32

// Main-kernel tiling
#define NTHREADS 256
#define R_TILE   32                 // rows per block
#define NSLICE   4                  // code slices (blocks = 256 * NSLICE = 1024)
#define SLICE_CODES (N_CODES / NSLICE)   // 4096
#define C_TILE   256                // codes per LDS tile
#define N_TILES  (SLICE_CODES / C_TILE)  // 16
#define CB_PAD   36                 // floats per code row in LDS (16B-aligned pad)

// ---------------------------------------------------------------------------
// Prep kernel: blocks 0..63 compute cc[n] = sum_d codebook[n][d]^2 (16384)
//              blocks 64..95 normalize z rows -> zn (in d_out) + zz (8192)
// Accumulation order identical to the previously-validated kernel (d ascending,
// sequential fmaf) so results stay bit-exact vs the numpy reference.
// ---------------------------------------------------------------------------
__global__ void vq_prep(const float* __restrict__ z,
                        const float* __restrict__ codebook,
                        float* __restrict__ zn,
                        float* __restrict__ zz,
                        float* __restrict__ cc) {
    int gid = blockIdx.x * NTHREADS + threadIdx.x;
    if (blockIdx.x < 64) {
        // cc for code gid
        const float* row = codebook + (size_t)gid * D_DIM;
        float s = 0.f;
#pragma unroll
        for (int d = 0; d < D_DIM; ++d) s = fmaf(row[d], row[d], s);
        cc[gid] = s;
    } else {
        int r = gid - N_CODES;      // 0..8191
        const float* row = z + (size_t)r * D_DIM;
        float s = 0.f;
#pragma unroll
        for (int d = 0; d < D_DIM; ++d) { float v = row[d]; s = fmaf(v, v, s); }
        float norm = sqrtf(s);
        norm = fmaxf(norm, 1e-12f);
        float zs = 0.f;
#pragma unroll
        for (int d = 0; d < D_DIM; ++d) {
            float v = row[d] / norm;       // IEEE division, matches reference
            zn[(size_t)r * D_DIM + d] = v;
            zs = fmaf(v, v, zs);
        }
        zz[r] = zs;
    }
}

// ---------------------------------------------------------------------------
// Main kernel: 1024 blocks = 256 row-blocks x 4 code-slices.
// Block: 32 rows vs 4096 codes. Thread: 8 rows x 4 codes register tile.
// Wave w (= rg) owns rows rg*8..rg*8+7 (wave-uniform -> z via scalar loads).
// Codebook tile staged in LDS row-major with stride 36 floats (144 B: 16B
// aligned, banks spread 8-way-uniform for both b128 writes and reads).
// ---------------------------------------------------------------------------
__global__ __launch_bounds__(NTHREADS, 4)
void vq_main(const float* __restrict__ zn,     // [8192][32] (lives in d_out)
             const float* __restrict__ zz,     // [8192]
             const float* __restrict__ codebook,
             const float* __restrict__ cc,     // [16384]
             float* __restrict__ pminv,        // [NSLICE][8192]
             int*   __restrict__ pmini) {      // [NSLICE][8192]
    __shared__ float cb_lds[C_TILE * CB_PAD];  // 36 KB

    const int tid   = threadIdx.x;
    const int rb    = blockIdx.x & 255;        // row-block
    const int slice = blockIdx.x >> 8;         // code slice
    const int rg    = tid >> 6;                // wave id = row group (0..3)
    const int cg    = tid & 63;                // lane = code group (0..63)

    const int row_base  = rb * R_TILE;
    const int code_base = slice * SLICE_CODES;

    // Wave-uniform row pointer -> scalar (s_load) path for z and zz.
    const int wrow = __builtin_amdgcn_readfirstlane(row_base + rg * 8);
    const float* zrow = zn + (size_t)wrow * D_DIM;

    float zzr[8];
#pragma unroll
    for (int r = 0; r < 8; ++r) zzr[r] = zz[wrow + r];

    float minv[8];
    int   mini[8];
#pragma unroll
    for (int r = 0; r < 8; ++r) { minv[r] = 3.4e38f; mini[r] = 0; }

    for (int t = 0; t < N_TILES; ++t) {
        const int base = code_base + t * C_TILE;
        __syncthreads();   // previous tile's LDS reads done
        // ---- stage: thread copies code (base+tid) into LDS (pad-36) ----
        {
            const float4* src = reinterpret_cast<const float4*>(
                codebook + (size_t)(base + tid) * D_DIM);
            float* dstf = &cb_lds[tid * CB_PAD];
#pragma unroll
            for (int k = 0; k < 8; ++k) {
                *reinterpret_cast<float4*>(dstf + k * 4) = src[k];
            }
        }
        __syncthreads();

        // ---- compute: acc[r=8 rows][j=4 codes], d in chunks of 4 ----
        float acc[8][4];
#pragma unroll
        for (int r = 0; r < 8; ++r)
#pragma unroll
            for (int j = 0; j < 4; ++j) acc[r][j] = 0.f;

#pragma unroll
        for (int dc = 0; dc < 8; ++dc) {
            float4 zv[8];
#pragma unroll
            for (int r = 0; r < 8; ++r) {
                zv[r] = *reinterpret_cast<const float4*>(zrow + r * D_DIM + dc * 4);
            }
#pragma unroll
            for (int j = 0; j < 4; ++j) {
                const float4 cb4 = *reinterpret_cast<const float4*>(
                    &cb_lds[(cg * 4 + j) * CB_PAD + dc * 4]);
#pragma unroll
                for (int r = 0; r < 8; ++r) {
                    // d-sequential accumulation (dc*4 + 0,1,2,3)
                    float a = acc[r][j];
                    a = fmaf(zv[r].x, cb4.x, a);
                    a = fmaf(zv[r].y, cb4.y, a);
                    a = fmaf(zv[r].z, cb4.z, a);
                    a = fmaf(zv[r].w, cb4.w, a);
                    acc[r][j] = a;
                }
            }
        }

        // ---- distances + argmin update ----
        const float4 cc4 = *reinterpret_cast<const float4*>(cc + base + cg * 4);
        const float ccarr[4] = {cc4.x, cc4.y, cc4.z, cc4.w};
#pragma unroll
        for (int j = 0; j < 4; ++j) {
            const int code = base + cg * 4 + j;
#pragma unroll
            for (int r = 0; r < 8; ++r) {
                float tsum = zzr[r] + ccarr[j];
                float dist = fmaf(-2.f, acc[r][j], tsum);
                if (dist < minv[r]) { minv[r] = dist; mini[r] = code; }
            }
        }
    }

    // ---- full-wave (64-lane) butterfly argmin reduce per row ----
#pragma unroll
    for (int r = 0; r < 8; ++r) {
        float v = minv[r];
        int   i = mini[r];
#pragma unroll
        for (int off = 32; off >= 1; off >>= 1) {
            float ov = __shfl_xor(v, off);
            int   oi = __shfl_xor(i, off);
            if (ov < v || (ov == v && oi < i)) { v = ov; i = oi; }
        }
        minv[r] = v; mini[r] = i;
    }
    if (cg == 0) {
#pragma unroll
        for (int r = 0; r < 8; ++r) {
            pminv[slice * M_ROWS + wrow + r] = minv[r];
            pmini[slice * M_ROWS + wrow + r] = mini[r];
        }
    }
}

// ---------------------------------------------------------------------------
// Final kernel: reduce 4 slice-partials per row (slices ascending in code
// index -> strict < keeps numpy first-min tie-break), gather z_q, write idx.
// ---------------------------------------------------------------------------
__global__ void vq_final(const float* __restrict__ codebook,
                         const float* __restrict__ pminv,
                         const int*   __restrict__ pmini,
                         float* __restrict__ zq,
                         float* __restrict__ idx_out) {
    int row = blockIdx.x * NTHREADS + threadIdx.x;   // 0..8191
    float bv = pminv[row];
    int   bi = pmini[row];
#pragma unroll
    for (int s = 1; s < NSLICE; ++s) {
        float v = pminv[s * M_ROWS + row];
        int   i = pmini[s * M_ROWS + row];
        if (v < bv || (v == bv && i < bi)) { bv = v; bi = i; }
    }
    idx_out[row] = (float)bi;
    const float4* src = reinterpret_cast<const float4*>(
        codebook + (size_t)bi * D_DIM);
    float4* dst = reinterpret_cast<float4*>(zq + (size_t)row * D_DIM);
#pragma unroll
    for (int k = 0; k < 8; ++k) dst[k] = src[k];
}

extern "C" void kernel_launch(void* const* d_in, const int* in_sizes, int n_in,
                              void* d_out, int out_size, void* d_ws, size_t ws_size,
                              hipStream_t stream) {
    const float* z        = (const float*)d_in[0];   // [8,1024,32]
    const float* codebook = (const float*)d_in[1];   // [16384,32]

    float* out     = (float*)d_out;
    float* zq_out  = out;                            // 262144 floats
    float* idx_out = out + (size_t)M_ROWS * D_DIM;   // 8192 floats

    // zn (normalized z) lives in the z_q output region until vq_final
    // overwrites it (vq_final never reads zn).
    float* zn = zq_out;

    // workspace layout (floats): cc[16384] | zz[8192] | pminv[4*8192] | pmini[4*8192]
    float* cc    = (float*)d_ws;
    float* zz    = cc + N_CODES;
    float* pminv = zz + M_ROWS;
    int*   pmini = (int*)(pminv + NSLICE * M_ROWS);

    vq_prep<<<96, NTHREADS, 0, stream>>>(z, codebook, zn, zz, cc);
    vq_main<<<256 * NSLICE, NTHREADS, 0, stream>>>(zn, zz, codebook, cc,
                                                   pminv, pmini);
    vq_final<<<M_ROWS / NTHREADS, NTHREADS, 0, stream>>>(codebook, pminv, pmini,
                                                         zq_out, idx_out);
}

// Round 3
// 175.112 us; speedup vs baseline: 1.6147x; 1.6147x over previous
//
#include <hip/hip_runtime.h>
#include <math.h>

// Problem constants
#define M_ROWS   8192     // B*S
#define N_CODES  16384
#define D_DIM    32

// Main-kernel tiling
#define NTHREADS 256
#define R_TILE   32                 // rows per block
#define NSLICE   4                  // code slices (blocks = 256 * NSLICE = 1024)
#define SLICE_CODES (N_CODES / NSLICE)   // 4096
#define C_TILE   256                // codes per LDS tile
#define N_TILES  (SLICE_CODES / C_TILE)  // 16
#define CB_PAD   36                 // floats per code row in LDS: 36%32==4 -> lane
                                    // stride 36 spreads b128 reads over all banks

// ---------------------------------------------------------------------------
// Prep kernel: blocks 0..63 compute cc[n] = sum_d codebook[n][d]^2 (16384)
//              blocks 64..95 normalize z rows -> zn (in d_out) + zz (8192)
// ---------------------------------------------------------------------------
__global__ void vq_prep(const float* __restrict__ z,
                        const float* __restrict__ codebook,
                        float* __restrict__ zn,
                        float* __restrict__ zz,
                        float* __restrict__ cc) {
    int gid = blockIdx.x * NTHREADS + threadIdx.x;
    if (blockIdx.x < 64) {
        const float* row = codebook + (size_t)gid * D_DIM;
        float s = 0.f;
#pragma unroll
        for (int d = 0; d < D_DIM; ++d) s = fmaf(row[d], row[d], s);
        cc[gid] = s;
    } else {
        int r = gid - N_CODES;      // 0..8191
        const float* row = z + (size_t)r * D_DIM;
        float s = 0.f;
#pragma unroll
        for (int d = 0; d < D_DIM; ++d) { float v = row[d]; s = fmaf(v, v, s); }
        float norm = sqrtf(s);
        norm = fmaxf(norm, 1e-12f);
        float zs = 0.f;
#pragma unroll
        for (int d = 0; d < D_DIM; ++d) {
            float v = row[d] / norm;       // IEEE division, matches reference
            zn[(size_t)r * D_DIM + d] = v;
            zs = fmaf(v, v, zs);
        }
        zz[r] = zs;
    }
}

// ---------------------------------------------------------------------------
// Main kernel: 1024 blocks = 256 row-blocks x 4 code-slices.
// Block: 32 rows vs 4096 codes. Thread: 8 rows x 4 codes register tile.
// Lane cg owns codes {base+cg, +64, +128, +192}  -> LDS lane stride = 36
// floats == bank stride 4 -> conflict-free b128 reads and writes.
// z rows for the wave live in zt (LDS) and are read via same-address
// broadcast ds_read_b128 (conflict-free by definition).
// LDS: 36864 (cb) + 4096 (zt) = 40960 B -> 4 blocks/CU = 160 KiB exactly.
// ---------------------------------------------------------------------------
__global__ __launch_bounds__(NTHREADS, 4)
void vq_main(const float* __restrict__ zn,     // [8192][32] (lives in d_out)
             const float* __restrict__ zz,     // [8192]
             const float* __restrict__ codebook,
             const float* __restrict__ cc,     // [16384]
             float* __restrict__ pminv,        // [NSLICE][8192]
             int*   __restrict__ pmini) {      // [NSLICE][8192]
    __shared__ float cb_lds[C_TILE * CB_PAD];  // 36 KB
    __shared__ float zt[R_TILE * D_DIM];       // 4 KB

    const int tid   = threadIdx.x;
    const int rb    = blockIdx.x & 255;        // row-block
    const int slice = blockIdx.x >> 8;         // code slice
    const int rg    = tid >> 6;                // wave id = row group (0..3)
    const int cg    = tid & 63;                // lane = code group (0..63)

    const int row_base  = rb * R_TILE;
    const int code_base = slice * SLICE_CODES;
    const int wrow      = row_base + rg * 8;   // wave's first row

    // ---- stage 32 normalized rows into zt (linear float4, conflict-free) ----
    {
        float4 v = *reinterpret_cast<const float4*>(zn + (size_t)row_base * D_DIM + tid * 4);
        *reinterpret_cast<float4*>(&zt[tid * 4]) = v;
    }

    float zzr[8];
#pragma unroll
    for (int r = 0; r < 8; ++r) zzr[r] = zz[wrow + r];

    float minv[8];
    int   mini[8];
#pragma unroll
    for (int r = 0; r < 8; ++r) { minv[r] = 3.4e38f; mini[r] = 0; }

    for (int t = 0; t < N_TILES; ++t) {
        const int base = code_base + t * C_TILE;
        __syncthreads();   // prev tile reads done (and zt staged, first iter)

        // ---- stage 256 codes: thread tid -> code base+tid, pad-36 row ----
        {
            const float4* src = reinterpret_cast<const float4*>(
                codebook + (size_t)(base + tid) * D_DIM);
            float* dstf = &cb_lds[tid * CB_PAD];
#pragma unroll
            for (int k = 0; k < 8; ++k) {
                *reinterpret_cast<float4*>(dstf + k * 4) = src[k];
            }
        }
        __syncthreads();

        // ---- compute: acc[8 rows][4 codes], d in chunks of 4 ----
        float acc[8][4];
#pragma unroll
        for (int r = 0; r < 8; ++r)
#pragma unroll
            for (int j = 0; j < 4; ++j) acc[r][j] = 0.f;

#pragma unroll
        for (int dc = 0; dc < 8; ++dc) {
            float4 cb4[4];
#pragma unroll
            for (int j = 0; j < 4; ++j) {
                cb4[j] = *reinterpret_cast<const float4*>(
                    &cb_lds[(cg + 64 * j) * CB_PAD + dc * 4]);
            }
#pragma unroll
            for (int r = 0; r < 8; ++r) {
                // same-address broadcast read (wave-uniform) — conflict-free
                const float4 zv = *reinterpret_cast<const float4*>(
                    &zt[(rg * 8 + r) * D_DIM + dc * 4]);
#pragma unroll
                for (int j = 0; j < 4; ++j) {
                    float a = acc[r][j];
                    a = fmaf(zv.x, cb4[j].x, a);
                    a = fmaf(zv.y, cb4[j].y, a);
                    a = fmaf(zv.z, cb4[j].z, a);
                    a = fmaf(zv.w, cb4[j].w, a);
                    acc[r][j] = a;
                }
            }
        }

        // ---- distances + argmin update (codes ascending in j) ----
#pragma unroll
        for (int j = 0; j < 4; ++j) {
            const int code = base + cg + 64 * j;
            const float ccj = cc[code];
#pragma unroll
            for (int r = 0; r < 8; ++r) {
                float tsum = zzr[r] + ccj;
                float dist = fmaf(-2.f, acc[r][j], tsum);
                if (dist < minv[r]) { minv[r] = dist; mini[r] = code; }
            }
        }
    }

    // ---- full-wave (64-lane) butterfly argmin reduce per row ----
#pragma unroll
    for (int r = 0; r < 8; ++r) {
        float v = minv[r];
        int   i = mini[r];
#pragma unroll
        for (int off = 32; off >= 1; off >>= 1) {
            float ov = __shfl_xor(v, off);
            int   oi = __shfl_xor(i, off);
            if (ov < v || (ov == v && oi < i)) { v = ov; i = oi; }
        }
        minv[r] = v; mini[r] = i;
    }
    if (cg == 0) {
#pragma unroll
        for (int r = 0; r < 8; ++r) {
            pminv[slice * M_ROWS + wrow + r] = minv[r];
            pmini[slice * M_ROWS + wrow + r] = mini[r];
        }
    }
}

// ---------------------------------------------------------------------------
// Final kernel: reduce 4 slice-partials per row (slices ascending in code
// index -> strict < keeps numpy first-min tie-break), gather z_q, write idx.
// ---------------------------------------------------------------------------
__global__ void vq_final(const float* __restrict__ codebook,
                         const float* __restrict__ pminv,
                         const int*   __restrict__ pmini,
                         float* __restrict__ zq,
                         float* __restrict__ idx_out) {
    int row = blockIdx.x * NTHREADS + threadIdx.x;   // 0..8191
    float bv = pminv[row];
    int   bi = pmini[row];
#pragma unroll
    for (int s = 1; s < NSLICE; ++s) {
        float v = pminv[s * M_ROWS + row];
        int   i = pmini[s * M_ROWS + row];
        if (v < bv || (v == bv && i < bi)) { bv = v; bi = i; }
    }
    idx_out[row] = (float)bi;
    const float4* src = reinterpret_cast<const float4*>(
        codebook + (size_t)bi * D_DIM);
    float4* dst = reinterpret_cast<float4*>(zq + (size_t)row * D_DIM);
#pragma unroll
    for (int k = 0; k < 8; ++k) dst[k] = src[k];
}

extern "C" void kernel_launch(void* const* d_in, const int* in_sizes, int n_in,
                              void* d_out, int out_size, void* d_ws, size_t ws_size,
                              hipStream_t stream) {
    const float* z        = (const float*)d_in[0];   // [8,1024,32]
    const float* codebook = (const float*)d_in[1];   // [16384,32]

    float* out     = (float*)d_out;
    float* zq_out  = out;                            // 262144 floats
    float* idx_out = out + (size_t)M_ROWS * D_DIM;   // 8192 floats

    // zn (normalized z) lives in the z_q output region until vq_final
    // overwrites it (vq_final never reads zn).
    float* zn = zq_out;

    // workspace layout (floats): cc[16384] | zz[8192] | pminv[4*8192] | pmini[4*8192]
    float* cc    = (float*)d_ws;
    float* zz    = cc + N_CODES;
    float* pminv = zz + M_ROWS;
    int*   pmini = (int*)(pminv + NSLICE * M_ROWS);

    vq_prep<<<96, NTHREADS, 0, stream>>>(z, codebook, zn, zz, cc);
    vq_main<<<256 * NSLICE, NTHREADS, 0, stream>>>(zn, zz, codebook, cc,
                                                   pminv, pmini);
    vq_final<<<M_ROWS / NTHREADS, NTHREADS, 0, stream>>>(codebook, pminv, pmini,
                                                         zq_out, idx_out);
}